// Round 6
// baseline (635.133 us; speedup 1.0000x reference)
//
#include <hip/hip_runtime.h>
#include <hip/hip_bf16.h>

#define T_TOK 8192
#define DMODEL 1024
#define DFF 4096
#define NEXP 8
#define CAP 1024

typedef __attribute__((ext_vector_type(8))) __bf16 bf16x8;
typedef __attribute__((ext_vector_type(4))) float f32x4;

__device__ __forceinline__ unsigned short f2bf(float f) {
  union { float f; unsigned int u; } v;
  v.f = f;
  return (unsigned short)((v.u + 0x7fffu + ((v.u >> 16) & 1u)) >> 16);
}

// A&S 7.1.26 erf (|err| <= 1.5e-7). gelu = 0.5 v (1+erf(v/sqrt2))
__device__ __forceinline__ float fast_gelu(float v) {
  float x = fabsf(v) * 0.70710678118654752440f;
  float t = __builtin_amdgcn_rcpf(1.0f + 0.3275911f * x);
  float poly = t * (0.254829592f + t * (-0.284496736f + t * (1.421413741f +
               t * (-1.453152027f + t * 1.061405429f))));
  float er = 1.0f - poly * __expf(-x * x);
  float s = (v >= 0.0f) ? er : -er;
  return 0.5f * v * (1.0f + s);
}

__device__ __forceinline__ void load_lds16(const unsigned short* g, unsigned short* l) {
  __builtin_amdgcn_global_load_lds((const __attribute__((address_space(1))) void*)g,
                                   (__attribute__((address_space(3))) void*)l,
                                   16, 0, 0);
}

// ---------------- router (fused x->bf16 convert + out zeroing): one wave per token --------------
__global__ void k_router(const float* __restrict__ x, const float* __restrict__ rw,
                         unsigned short* __restrict__ xb,
                         int* __restrict__ tk_idx, float* __restrict__ tk_w,
                         float* __restrict__ out) {
  int wv = threadIdx.x >> 6, lane = threadIdx.x & 63;
  int t = blockIdx.x * 4 + wv;
  // zero this token's output row (gemm2 atomically accumulates into it)
  {
    float4 z = {0.f, 0.f, 0.f, 0.f};
    float4* orow = (float4*)(out + (size_t)t * DMODEL);
#pragma unroll
    for (int j = 0; j < 4; ++j) orow[j * 64 + lane] = z;
  }
  const float4* xr = (const float4*)(x + (size_t)t * DMODEL);
  uint2* xbw = (uint2*)(xb + (size_t)t * DMODEL);
  float acc[NEXP];
#pragma unroll
  for (int e = 0; e < NEXP; ++e) acc[e] = 0.f;
#pragma unroll
  for (int j = 0; j < DMODEL / 256; ++j) {
    float4 v = xr[j * 64 + lane];
#pragma unroll
    for (int e = 0; e < NEXP; ++e) {
      float4 w = ((const float4*)(rw + e * DMODEL))[j * 64 + lane];
      acc[e] += v.x * w.x + v.y * w.y + v.z * w.z + v.w * w.w;
    }
    uint2 p;
    p.x = (unsigned int)f2bf(v.x) | ((unsigned int)f2bf(v.y) << 16);
    p.y = (unsigned int)f2bf(v.z) | ((unsigned int)f2bf(v.w) << 16);
    xbw[j * 64 + lane] = p;
  }
#pragma unroll
  for (int e = 0; e < NEXP; ++e)
    for (int off = 32; off; off >>= 1) acc[e] += __shfl_xor(acc[e], off);
  if (lane == 0) {
    int i0 = 0;
    for (int e = 1; e < NEXP; ++e) if (acc[e] > acc[i0]) i0 = e;
    int i1 = (i0 == 0) ? 1 : 0;
    for (int e = 0; e < NEXP; ++e) if (e != i0 && acc[e] > acc[i1]) i1 = e;
    float ex = expf(acc[i1] - acc[i0]);  // <= 1
    float w0 = 1.f / (1.f + ex);
    float w1 = ex / (1.f + ex);
    tk_idx[2 * t] = i0; tk_idx[2 * t + 1] = i1;
    tk_w[2 * t] = w0;  tk_w[2 * t + 1] = w1;
  }
}

// ---------------- fp32 [E][Kd][Nd] -> bf16 [E][Nd][Kd] ----------------
__global__ void k_transpose_cvt(const float* __restrict__ src, unsigned short* __restrict__ dst,
                                int Kd, int Nd) {
  __shared__ unsigned short tile[64][73];
  int e = blockIdx.z;
  size_t k0 = (size_t)blockIdx.y * 64, n0 = (size_t)blockIdx.x * 64;
  int tid = threadIdx.x;
  const float* sb = src + (size_t)e * Kd * Nd;
  int r = tid >> 4, cg = (tid & 15) * 4;
  for (int rr = 0; rr < 4; ++rr) {
    int row = r + rr * 16;
    float4 v = *(const float4*)(sb + (k0 + row) * Nd + n0 + cg);
    tile[row][cg + 0] = f2bf(v.x);
    tile[row][cg + 1] = f2bf(v.y);
    tile[row][cg + 2] = f2bf(v.z);
    tile[row][cg + 3] = f2bf(v.w);
  }
  __syncthreads();
  unsigned short* db = dst + (size_t)e * Nd * Kd;
  int rn = tid >> 3, kg = (tid & 7) * 8;
  for (int rr = 0; rr < 2; ++rr) {
    int nrow = rn + rr * 32;
    union { unsigned short h[8]; uint4 v; } o;
#pragma unroll
    for (int j = 0; j < 8; ++j) o.h[j] = tile[kg + j][nrow];
    *(uint4*)(db + (n0 + nrow) * Kd + k0 + kg) = o.v;
  }
}

// ---------------- capacity scan: one block per expert, token order, 2 barriers ----------------
__global__ void k_scan(const int* __restrict__ tk_idx, const float* __restrict__ tk_w,
                       int* __restrict__ etok, float* __restrict__ egate,
                       int* __restrict__ counts) {
  __shared__ int wavecnt[8][16];
  __shared__ int waveoff[8][16];
  int e = blockIdx.x;
  int tid = threadIdx.x, lane = tid & 63, wv = tid >> 6;
  for (int i = tid; i < CAP; i += 1024) {
    etok[e * CAP + i] = 0;
    egate[e * CAP + i] = 0.f;   // gemm2 reads ALL slots now: empty slots must be gate 0
  }
  unsigned long long lt = (1ULL << lane) - 1ULL;
  int pos[8], wh[8];
  bool mine[8];
#pragma unroll
  for (int c = 0; c < 8; ++c) {
    int t = c * 1024 + tid;
    int e0 = tk_idx[2 * t], e1 = tk_idx[2 * t + 1];
    bool is0 = (e0 == e), is1 = (e1 == e);
    mine[c] = is0 || is1;
    wh[c] = is1 ? 1 : 0;
    unsigned long long bal = __ballot(mine[c]);
    pos[c] = __popcll(bal & lt);
    if (lane == 0) wavecnt[c][wv] = __popcll(bal);
  }
  __syncthreads();
  if (tid == 0) {
    int s = 0;
    for (int c = 0; c < 8; ++c)
      for (int w = 0; w < 16; ++w) { waveoff[c][w] = s; s += wavecnt[c][w]; }
    counts[e] = s;  // uncapped total (for lb_loss)
  }
  __syncthreads();
#pragma unroll
  for (int c = 0; c < 8; ++c) {
    if (mine[c]) {
      int t = c * 1024 + tid;
      int r = waveoff[c][wv] + pos[c];
      if (r < CAP) {
        etok[e * CAP + r] = t;
        egate[e * CAP + r] = tk_w[2 * t + wh[c]];
      }
    }
  }
}

// ---------------- GEMM1: H[e] = gelu(X[etok[e]] @ w1[e] + b1[e]) -> bf16 ----------------
// Counted-vmcnt 3-buffer pipeline (one raw barrier per K-step, vmcnt never drained in-loop).
// Block mapping: e = bid>>8, nl = bid&7 -> per-XCD L2 live set ~3 MiB < 4 MiB.
__global__ __launch_bounds__(256) void k_gemm1(
    const unsigned short* __restrict__ xb, const unsigned short* __restrict__ w1t,
    const float* __restrict__ b1, const int* __restrict__ etok,
    unsigned short* __restrict__ H) {
  __shared__ __align__(16) unsigned short smem[24576];  // 48 KB: 3 bufs x (A 8KB + B 8KB)
  int tid = threadIdx.x;
  int lane = tid & 63, wv = tid >> 6;
  int bid = blockIdx.x;
  int e = bid >> 8;
  int b = bid & 255;
  int nl = b & 7, m = (b >> 3) & 7, nh = b >> 6;
  int m0 = m * 128, n0 = (nh * 8 + nl) * 128;

  const unsigned short* gA[2];
  const unsigned short* gB[2];
  int wb[2];
#pragma unroll
  for (int s = 0; s < 2; ++s) {
    int i = s * 256 + tid;
    int row = i >> 2;
    int q = (i & 3) ^ ((i >> 3) & 3);  // pre-swizzled source chunk = c ^ ((row>>1)&3)
    int tok = etok[e * CAP + m0 + row];
    gA[s] = xb + (size_t)tok * DMODEL + q * 8;
    gB[s] = w1t + ((size_t)e * DFF + n0 + row) * DMODEL + q * 8;
    wb[s] = (s * 256 + wv * 64) * 8;
  }

  f32x4 zero = {0.f, 0.f, 0.f, 0.f};
  f32x4 acc[4][4];
#pragma unroll
  for (int mi = 0; mi < 4; ++mi)
#pragma unroll
    for (int ni = 0; ni < 4; ++ni) acc[mi][ni] = zero;

  int wm = (wv >> 1) * 64, wn = (wv & 1) * 64;
  int fr = lane & 15, quad = lane >> 4;
  int cs = (quad ^ ((fr >> 1) & 3)) * 8;  // conflict-free slot within 64B row
  int aoff = (wm + fr) * 32 + cs;
  int boff = (wn + fr) * 32 + cs;

  // prologue: stage K-slices 0 and 1 into buffers 0 and 1 (8 loads in flight)
#pragma unroll
  for (int s = 0; s < 2; ++s) {
    load_lds16(gA[s], smem + wb[s]);
    load_lds16(gB[s], smem + 4096 + wb[s]);
  }
#pragma unroll
  for (int s = 0; s < 2; ++s) {
    load_lds16(gA[s] + 32, smem + 8192 + wb[s]);
    load_lds16(gB[s] + 32, smem + 8192 + 4096 + wb[s]);
  }

  const int NT = DMODEL / 32;  // 32
  int cur = 0, stg = 16384;
  for (int t = 0; t < NT; ++t) {
    // own stage(t) loads landed (4 newest stay in flight); then all waves' via barrier
    if (t < NT - 1) asm volatile("s_waitcnt vmcnt(4)" ::: "memory");
    else            asm volatile("s_waitcnt vmcnt(0)" ::: "memory");
    __builtin_amdgcn_s_barrier();
    asm volatile("" ::: "memory");  // pin ds_reads below the barrier
    if (t + 2 < NT) {               // prefetch slice t+2 into the buffer read at t-1
      int kp = (t + 2) * 32;
#pragma unroll
      for (int s = 0; s < 2; ++s) {
        load_lds16(gA[s] + kp, smem + stg + wb[s]);
        load_lds16(gB[s] + kp, smem + stg + 4096 + wb[s]);
      }
      stg += 8192; if (stg == 24576) stg = 0;
    }
    const unsigned short* Ab = smem + cur;
    const unsigned short* Bb = Ab + 4096;
    bf16x8 av[4], bv[4];
#pragma unroll
    for (int mi = 0; mi < 4; ++mi) av[mi] = *(const bf16x8*)(Ab + aoff + mi * 512);
#pragma unroll
    for (int ni = 0; ni < 4; ++ni) bv[ni] = *(const bf16x8*)(Bb + boff + ni * 512);
#pragma unroll
    for (int mi = 0; mi < 4; ++mi)
#pragma unroll
      for (int ni = 0; ni < 4; ++ni)
        acc[mi][ni] = __builtin_amdgcn_mfma_f32_16x16x32_bf16(bv[ni], av[mi], acc[mi][ni], 0, 0, 0);
    cur += 8192; if (cur == 24576) cur = 0;
  }
  __syncthreads();

  unsigned short* EP = smem + wv * 1536;
#pragma unroll
  for (int ni = 0; ni < 4; ++ni) {
    float4 b4 = *(const float4*)(b1 + e * DFF + n0 + wn + ni * 16 + quad * 4);
#pragma unroll
    for (int mi = 0; mi < 4; ++mi) {
      float v0 = fast_gelu(acc[mi][ni][0] + b4.x);
      float v1 = fast_gelu(acc[mi][ni][1] + b4.y);
      float v2 = fast_gelu(acc[mi][ni][2] + b4.z);
      float v3 = fast_gelu(acc[mi][ni][3] + b4.w);
      uint2 p;
      p.x = (unsigned int)f2bf(v0) | ((unsigned int)f2bf(v1) << 16);
      p.y = (unsigned int)f2bf(v2) | ((unsigned int)f2bf(v3) << 16);
      *(uint2*)(EP + (mi * 16 + fr) * 24 + quad * 4) = p;
    }
#pragma unroll
    for (int t = 0; t < 2; ++t) {
      int row = t * 32 + (lane >> 1), chunk = lane & 1;
      uint4 v = *(const uint4*)(EP + row * 24 + chunk * 8);
      *(uint4*)(H + ((size_t)e * CAP + m0 + wm + row) * DFF + n0 + wn + ni * 16 + chunk * 8) = v;
    }
  }
}

// ---------------- GEMM2 + fused combine: out[tok] += gate * (H[slot] @ w2[e] + b2[e]) ---------
// 64x128 tiles -> 1024 blocks (4-5 resident blocks/CU, ~20 waves/CU hides the 2-phase stall).
// 2-phase double-buffered, swizzled LDS, expert==XCD (bid&7). fp32 atomic epilogue (2 addends
// per element, commutative -> deterministic).
__global__ __launch_bounds__(256) void k_gemm2(
    const unsigned short* __restrict__ H, const unsigned short* __restrict__ w2t,
    const float* __restrict__ b2, const int* __restrict__ etok,
    const float* __restrict__ egate, const int* __restrict__ counts,
    float* __restrict__ out, float* __restrict__ loss_out) {
  __shared__ __align__(16) unsigned short smem[12288];  // 24 KB: 2 bufs x (A 4KB + B 8KB)
  int tid = threadIdx.x;
  int lane = tid & 63, wv = tid >> 6;
  int bid = blockIdx.x;
  if (bid == 0 && tid == 0) {   // lb_loss (counts ready since k_scan)
    float loss = 0.f;
    for (int ee = 0; ee < NEXP; ++ee) {
      float d = (float)counts[ee] - 2048.0f;
      loss += d * d;
    }
    loss_out[0] = loss / (8192.0f * 8192.0f);
  }
  int e = bid & 7;              // expert pinned to one XCD; 128 blocks co-resident there
  int r = bid >> 3;
  int n0 = (r & 7) * 128;
  int m0 = (r >> 3) * 64;

  const unsigned short* g[3];
  int wb[3];
#pragma unroll
  for (int s = 0; s < 3; ++s) {
    int i = s * 256 + tid;
    wb[s] = i * 8;
    if (s == 0) {               // A: 64 rows x 4 chunks
      int row = i >> 2;
      int q = (i & 3) ^ ((i >> 3) & 3);
      g[s] = H + ((size_t)e * CAP + m0 + row) * DFF + q * 8;
    } else {                    // B: 128 rows x 4 chunks
      int ii = i - 256;
      int row = ii >> 2;
      int q = (ii & 3) ^ ((ii >> 3) & 3);
      g[s] = w2t + ((size_t)e * DMODEL + n0 + row) * DFF + q * 8;
    }
  }

  f32x4 zero = {0.f, 0.f, 0.f, 0.f};
  f32x4 acc[4][2];
#pragma unroll
  for (int mi = 0; mi < 4; ++mi)
#pragma unroll
    for (int ni = 0; ni < 2; ++ni) acc[mi][ni] = zero;

  int wn = wv * 32;             // wave tile: 64m x 32n
  int fr = lane & 15, quad = lane >> 4;
  int cs = (quad ^ ((fr >> 1) & 3)) * 8;  // conflict-free slot within 64B row
  int aoff = fr * 32 + cs;
  int boff = (wn + fr) * 32 + cs;

#pragma unroll
  for (int s = 0; s < 3; ++s) load_lds16(g[s], smem + wb[s]);  // prologue: slice 0 -> buf0
  int buf = 0;
  for (int k0 = 32; k0 <= DFF; k0 += 32) {
    __syncthreads();            // drains vmcnt(0): previous stage complete; guards reuse
    int nbuf = buf ^ 6144;
    if (k0 < DFF) {
#pragma unroll
      for (int s = 0; s < 3; ++s) load_lds16(g[s] + k0, smem + nbuf + wb[s]);
    }
    const unsigned short* Ab = smem + buf;
    const unsigned short* Bb = Ab + 2048;
    bf16x8 av[4], bv[2];
#pragma unroll
    for (int mi = 0; mi < 4; ++mi) av[mi] = *(const bf16x8*)(Ab + aoff + mi * 512);
#pragma unroll
    for (int ni = 0; ni < 2; ++ni) bv[ni] = *(const bf16x8*)(Bb + boff + ni * 512);
#pragma unroll
    for (int mi = 0; mi < 4; ++mi)
#pragma unroll
      for (int ni = 0; ni < 2; ++ni)
        acc[mi][ni] = __builtin_amdgcn_mfma_f32_16x16x32_bf16(bv[ni], av[mi], acc[mi][ni], 0, 0, 0);
    buf = nbuf;
  }

  // fused-combine epilogue: no LDS needed; acc[mi][ni][j] is (row m0+mi*16+fr, col n0+wn+ni*16+quad*4+j)
  int slotbase = e * CAP + m0;
#pragma unroll
  for (int mi = 0; mi < 4; ++mi) {
    int slot = slotbase + mi * 16 + fr;
    float gate = egate[slot];
    if (gate != 0.f) {
      int tok = etok[slot];
      float* orow = out + (size_t)tok * DMODEL + n0 + wn + quad * 4;
#pragma unroll
      for (int ni = 0; ni < 2; ++ni) {
        float4 b4 = *(const float4*)(b2 + e * DMODEL + n0 + wn + ni * 16 + quad * 4);
        atomicAdd(orow + ni * 16 + 0, gate * (acc[mi][ni][0] + b4.x));
        atomicAdd(orow + ni * 16 + 1, gate * (acc[mi][ni][1] + b4.y));
        atomicAdd(orow + ni * 16 + 2, gate * (acc[mi][ni][2] + b4.z));
        atomicAdd(orow + ni * 16 + 3, gate * (acc[mi][ni][3] + b4.w));
      }
    }
  }
}

extern "C" void kernel_launch(void* const* d_in, const int* in_sizes, int n_in,
                              void* d_out, int out_size, void* d_ws, size_t ws_size,
                              hipStream_t stream) {
  (void)in_sizes; (void)n_in; (void)ws_size; (void)out_size;
  const float* x  = (const float*)d_in[0];
  const float* rw = (const float*)d_in[1];
  const float* w1 = (const float*)d_in[2];
  const float* b1 = (const float*)d_in[3];
  const float* w2 = (const float*)d_in[4];
  const float* b2 = (const float*)d_in[5];
  float* out = (float*)d_out;

  char* ws = (char*)d_ws;
  const size_t XB_BYTES = (size_t)T_TOK * DMODEL * 2;          // 16 MiB
  const size_t WT_BYTES = (size_t)NEXP * DFF * DMODEL * 2;     // 64 MiB (w1t, then w2t)
  const size_t H_BYTES  = (size_t)NEXP * CAP * DFF * 2;        // 64 MiB
  unsigned short* xb = (unsigned short*)ws;
  unsigned short* wT = (unsigned short*)(ws + XB_BYTES);
  unsigned short* Hb = (unsigned short*)(ws + XB_BYTES + WT_BYTES);
  char* small = ws + XB_BYTES + WT_BYTES + H_BYTES;
  int*   etok   = (int*)small;                                  // 32 KB
  float* egate  = (float*)(small + NEXP * CAP * 4);             // 32 KB
  int*   tkidx  = (int*)(small + 2 * NEXP * CAP * 4);           // 64 KB
  float* tkw    = (float*)(small + 2 * NEXP * CAP * 4 + T_TOK * 2 * 4);  // 64 KB
  int*   counts = (int*)(small + 2 * NEXP * CAP * 4 + 2 * T_TOK * 2 * 4);// 32 B

  k_router<<<T_TOK / 4, 256, 0, stream>>>(x, rw, xb, tkidx, tkw, out);
  k_scan<<<NEXP, 1024, 0, stream>>>(tkidx, tkw, etok, egate, counts);
  k_transpose_cvt<<<dim3(DFF / 64, DMODEL / 64, NEXP), 256, 0, stream>>>(w1, wT, DMODEL, DFF);
  k_gemm1<<<NEXP * 256, 256, 0, stream>>>(xb, wT, b1, etok, Hb);
  k_transpose_cvt<<<dim3(DMODEL / 64, DFF / 64, NEXP), 256, 0, stream>>>(w2, wT, DFF, DMODEL);
  k_gemm2<<<NEXP * 128, 256, 0, stream>>>(Hb, wT, b2, etok, egate, counts, out,
                                          out + (size_t)T_TOK * DMODEL);
}

// Round 7
// 535.068 us; speedup vs baseline: 1.1870x; 1.1870x over previous
//
#include <hip/hip_runtime.h>
#include <hip/hip_bf16.h>

#define T_TOK 8192
#define DMODEL 1024
#define DFF 4096
#define NEXP 8
#define CAP 1024

typedef __attribute__((ext_vector_type(8))) __bf16 bf16x8;
typedef __attribute__((ext_vector_type(4))) float f32x4;

__device__ __forceinline__ unsigned short f2bf(float f) {
  union { float f; unsigned int u; } v;
  v.f = f;
  return (unsigned short)((v.u + 0x7fffu + ((v.u >> 16) & 1u)) >> 16);
}

__device__ __forceinline__ float bfbits2f(unsigned int lo16) {
  union { unsigned int u; float f; } v; v.u = lo16 << 16; return v.f;
}

// A&S 7.1.26 erf (|err| <= 1.5e-7). gelu = 0.5 v (1+erf(v/sqrt2))
__device__ __forceinline__ float fast_gelu(float v) {
  float x = fabsf(v) * 0.70710678118654752440f;
  float t = __builtin_amdgcn_rcpf(1.0f + 0.3275911f * x);
  float poly = t * (0.254829592f + t * (-0.284496736f + t * (1.421413741f +
               t * (-1.453152027f + t * 1.061405429f))));
  float er = 1.0f - poly * __expf(-x * x);
  float s = (v >= 0.0f) ? er : -er;
  return 0.5f * v * (1.0f + s);
}

__device__ __forceinline__ void load_lds16(const unsigned short* g, unsigned short* l) {
  __builtin_amdgcn_global_load_lds((const __attribute__((address_space(1))) void*)g,
                                   (__attribute__((address_space(3))) void*)l,
                                   16, 0, 0);
}

// ---------------- role: router (x->bf16 convert + top-2 + tinv init), one wave per token -------
__device__ __forceinline__ void router_role(
    const float* __restrict__ x, const float* __restrict__ rw,
    unsigned short* __restrict__ xb, int* __restrict__ tk_idx,
    float* __restrict__ tk_w, int* __restrict__ tinv, int rbid, int tid) {
  if (tid < 8) tinv[rbid * 8 + tid] = -1;  // tokens 4b..4b+3, K=2
  int wv = tid >> 6, lane = tid & 63;
  int t = rbid * 4 + wv;
  const float4* xr = (const float4*)(x + (size_t)t * DMODEL);
  uint2* xbw = (uint2*)(xb + (size_t)t * DMODEL);
  float acc[NEXP];
#pragma unroll
  for (int e = 0; e < NEXP; ++e) acc[e] = 0.f;
#pragma unroll
  for (int j = 0; j < DMODEL / 256; ++j) {
    float4 v = xr[j * 64 + lane];
#pragma unroll
    for (int e = 0; e < NEXP; ++e) {
      float4 w = ((const float4*)(rw + e * DMODEL))[j * 64 + lane];
      acc[e] += v.x * w.x + v.y * w.y + v.z * w.z + v.w * w.w;
    }
    uint2 p;
    p.x = (unsigned int)f2bf(v.x) | ((unsigned int)f2bf(v.y) << 16);
    p.y = (unsigned int)f2bf(v.z) | ((unsigned int)f2bf(v.w) << 16);
    xbw[j * 64 + lane] = p;
  }
#pragma unroll
  for (int e = 0; e < NEXP; ++e)
    for (int off = 32; off; off >>= 1) acc[e] += __shfl_xor(acc[e], off);
  if (lane == 0) {
    int i0 = 0;
    for (int e = 1; e < NEXP; ++e) if (acc[e] > acc[i0]) i0 = e;
    int i1 = (i0 == 0) ? 1 : 0;
    for (int e = 0; e < NEXP; ++e) if (e != i0 && acc[e] > acc[i1]) i1 = e;
    float ex = expf(acc[i1] - acc[i0]);  // <= 1
    float w0 = 1.f / (1.f + ex);
    float w1 = ex / (1.f + ex);
    tk_idx[2 * t] = i0; tk_idx[2 * t + 1] = i1;
    tk_w[2 * t] = w0;  tk_w[2 * t + 1] = w1;
  }
}

// ---------------- role: fp32 [E][Kd][Nd] -> bf16 [E][Nd][Kd] (64x64 tile) ----------------
__device__ __forceinline__ void trans_role(
    const float* __restrict__ src, unsigned short* __restrict__ dst,
    int Kd, int Nd, int bx, int by, int e, int tid) {
  __shared__ unsigned short tile[64][73];
  size_t k0 = (size_t)by * 64, n0 = (size_t)bx * 64;
  const float* sb = src + (size_t)e * Kd * Nd;
  int r = tid >> 4, cg = (tid & 15) * 4;
  for (int rr = 0; rr < 4; ++rr) {
    int row = r + rr * 16;
    float4 v = *(const float4*)(sb + (k0 + row) * Nd + n0 + cg);
    tile[row][cg + 0] = f2bf(v.x);
    tile[row][cg + 1] = f2bf(v.y);
    tile[row][cg + 2] = f2bf(v.z);
    tile[row][cg + 3] = f2bf(v.w);
  }
  __syncthreads();
  unsigned short* db = dst + (size_t)e * Nd * Kd;
  int rn = tid >> 3, kg = (tid & 7) * 8;
  for (int rr = 0; rr < 2; ++rr) {
    int nrow = rn + rr * 32;
    union { unsigned short h[8]; uint4 v; } o;
#pragma unroll
    for (int j = 0; j < 8; ++j) o.h[j] = tile[kg + j][nrow];
    *(uint4*)(db + (n0 + nrow) * Kd + k0 + kg) = o.v;
  }
}

// ---------------- fused prep: router (2048 blocks) + transpose w1 (8192) [+ transpose w2] -----
__global__ __launch_bounds__(256) void k_prep(
    const float* __restrict__ x, const float* __restrict__ rw,
    unsigned short* __restrict__ xb, int* __restrict__ tkidx,
    float* __restrict__ tkw, int* __restrict__ tinv,
    const float* __restrict__ w1, unsigned short* __restrict__ w1t,
    const float* __restrict__ w2, unsigned short* __restrict__ w2t) {
  int bid = blockIdx.x, tid = threadIdx.x;
  if (bid < 2048) { router_role(x, rw, xb, tkidx, tkw, tinv, bid, tid); return; }
  bid -= 2048;
  if (bid < 8192) {  // w1: Kd=DMODEL, Nd=DFF, grid (64,16,8)
    trans_role(w1, w1t, DMODEL, DFF, bid & 63, (bid >> 6) & 15, bid >> 10, tid);
    return;
  }
  bid -= 8192;       // w2: Kd=DFF, Nd=DMODEL, grid (16,64,8)
  trans_role(w2, w2t, DFF, DMODEL, bid & 15, (bid >> 4) & 63, bid >> 10, tid);
}

// standalone transpose for the fallback (shared wT buffer) path
__global__ __launch_bounds__(256) void k_transpose_cvt(
    const float* __restrict__ src, unsigned short* __restrict__ dst, int Kd, int Nd) {
  trans_role(src, dst, Kd, Nd, blockIdx.x, blockIdx.y, blockIdx.z, threadIdx.x);
}

// ---------------- capacity scan: one block per expert, token order, 2 barriers ----------------
__global__ void k_scan(const int* __restrict__ tk_idx, const float* __restrict__ tk_w,
                       int* __restrict__ etok, float* __restrict__ egate,
                       int* __restrict__ tinv, int* __restrict__ counts) {
  __shared__ int wavecnt[8][16];
  __shared__ int waveoff[8][16];
  int e = blockIdx.x;
  int tid = threadIdx.x, lane = tid & 63, wv = tid >> 6;
  for (int i = tid; i < CAP; i += 1024) etok[e * CAP + i] = 0;
  unsigned long long lt = (1ULL << lane) - 1ULL;
  int pos[8], wh[8];
  bool mine[8];
#pragma unroll
  for (int c = 0; c < 8; ++c) {
    int t = c * 1024 + tid;
    int e0 = tk_idx[2 * t], e1 = tk_idx[2 * t + 1];
    bool is0 = (e0 == e), is1 = (e1 == e);
    mine[c] = is0 || is1;
    wh[c] = is1 ? 1 : 0;
    unsigned long long bal = __ballot(mine[c]);
    pos[c] = __popcll(bal & lt);
    if (lane == 0) wavecnt[c][wv] = __popcll(bal);
  }
  __syncthreads();
  if (tid == 0) {
    int s = 0;
    for (int c = 0; c < 8; ++c)
      for (int w = 0; w < 16; ++w) { waveoff[c][w] = s; s += wavecnt[c][w]; }
    counts[e] = s;  // uncapped total (for lb_loss)
  }
  __syncthreads();
#pragma unroll
  for (int c = 0; c < 8; ++c) {
    if (mine[c]) {
      int t = c * 1024 + tid;
      int r = waveoff[c][wv] + pos[c];
      if (r < CAP) {
        etok[e * CAP + r] = t;
        egate[e * CAP + r] = tk_w[2 * t + wh[c]];
        tinv[2 * t + wh[c]] = e * CAP + r;
      }
    }
  }
}

// ---------------- GEMM1: H[e] = gelu(X[etok[e]] @ w1[e] + b1[e]) -> bf16 ----------------
// Counted-vmcnt 3-buffer pipeline (measured 108.9 us). e = bid>>8, nl = bid&7 -> L2-fit live set.
__global__ __launch_bounds__(256) void k_gemm1(
    const unsigned short* __restrict__ xb, const unsigned short* __restrict__ w1t,
    const float* __restrict__ b1, const int* __restrict__ etok,
    unsigned short* __restrict__ H) {
  __shared__ __align__(16) unsigned short smem[24576];  // 48 KB: 3 bufs x (A 8KB + B 8KB)
  int tid = threadIdx.x;
  int lane = tid & 63, wv = tid >> 6;
  int bid = blockIdx.x;
  int e = bid >> 8;
  int b = bid & 255;
  int nl = b & 7, m = (b >> 3) & 7, nh = b >> 6;
  int m0 = m * 128, n0 = (nh * 8 + nl) * 128;

  const unsigned short* gA[2];
  const unsigned short* gB[2];
  int wb[2];
#pragma unroll
  for (int s = 0; s < 2; ++s) {
    int i = s * 256 + tid;
    int row = i >> 2;
    int q = (i & 3) ^ ((i >> 3) & 3);  // pre-swizzled source chunk = c ^ ((row>>1)&3)
    int tok = etok[e * CAP + m0 + row];
    gA[s] = xb + (size_t)tok * DMODEL + q * 8;
    gB[s] = w1t + ((size_t)e * DFF + n0 + row) * DMODEL + q * 8;
    wb[s] = (s * 256 + wv * 64) * 8;
  }

  f32x4 zero = {0.f, 0.f, 0.f, 0.f};
  f32x4 acc[4][4];
#pragma unroll
  for (int mi = 0; mi < 4; ++mi)
#pragma unroll
    for (int ni = 0; ni < 4; ++ni) acc[mi][ni] = zero;

  int wm = (wv >> 1) * 64, wn = (wv & 1) * 64;
  int fr = lane & 15, quad = lane >> 4;
  int cs = (quad ^ ((fr >> 1) & 3)) * 8;  // conflict-free slot within 64B row
  int aoff = (wm + fr) * 32 + cs;
  int boff = (wn + fr) * 32 + cs;

  // prologue: stage K-slices 0 and 1 into buffers 0 and 1 (8 loads in flight)
#pragma unroll
  for (int s = 0; s < 2; ++s) {
    load_lds16(gA[s], smem + wb[s]);
    load_lds16(gB[s], smem + 4096 + wb[s]);
  }
#pragma unroll
  for (int s = 0; s < 2; ++s) {
    load_lds16(gA[s] + 32, smem + 8192 + wb[s]);
    load_lds16(gB[s] + 32, smem + 8192 + 4096 + wb[s]);
  }

  const int NT = DMODEL / 32;  // 32
  int cur = 0, stg = 16384;
  for (int t = 0; t < NT; ++t) {
    if (t < NT - 1) asm volatile("s_waitcnt vmcnt(4)" ::: "memory");
    else            asm volatile("s_waitcnt vmcnt(0)" ::: "memory");
    __builtin_amdgcn_s_barrier();
    asm volatile("" ::: "memory");  // pin ds_reads below the barrier
    if (t + 2 < NT) {               // prefetch slice t+2 into the buffer read at t-1
      int kp = (t + 2) * 32;
#pragma unroll
      for (int s = 0; s < 2; ++s) {
        load_lds16(gA[s] + kp, smem + stg + wb[s]);
        load_lds16(gB[s] + kp, smem + stg + 4096 + wb[s]);
      }
      stg += 8192; if (stg == 24576) stg = 0;
    }
    const unsigned short* Ab = smem + cur;
    const unsigned short* Bb = Ab + 4096;
    bf16x8 av[4], bv[4];
#pragma unroll
    for (int mi = 0; mi < 4; ++mi) av[mi] = *(const bf16x8*)(Ab + aoff + mi * 512);
#pragma unroll
    for (int ni = 0; ni < 4; ++ni) bv[ni] = *(const bf16x8*)(Bb + boff + ni * 512);
#pragma unroll
    for (int mi = 0; mi < 4; ++mi)
#pragma unroll
      for (int ni = 0; ni < 4; ++ni)
        acc[mi][ni] = __builtin_amdgcn_mfma_f32_16x16x32_bf16(bv[ni], av[mi], acc[mi][ni], 0, 0, 0);
    cur += 8192; if (cur == 24576) cur = 0;
  }
  __syncthreads();

  unsigned short* EP = smem + wv * 1536;
#pragma unroll
  for (int ni = 0; ni < 4; ++ni) {
    float4 b4 = *(const float4*)(b1 + e * DFF + n0 + wn + ni * 16 + quad * 4);
#pragma unroll
    for (int mi = 0; mi < 4; ++mi) {
      float v0 = fast_gelu(acc[mi][ni][0] + b4.x);
      float v1 = fast_gelu(acc[mi][ni][1] + b4.y);
      float v2 = fast_gelu(acc[mi][ni][2] + b4.z);
      float v3 = fast_gelu(acc[mi][ni][3] + b4.w);
      uint2 p;
      p.x = (unsigned int)f2bf(v0) | ((unsigned int)f2bf(v1) << 16);
      p.y = (unsigned int)f2bf(v2) | ((unsigned int)f2bf(v3) << 16);
      *(uint2*)(EP + (mi * 16 + fr) * 24 + quad * 4) = p;
    }
#pragma unroll
    for (int t = 0; t < 2; ++t) {
      int row = t * 32 + (lane >> 1), chunk = lane & 1;
      uint4 v = *(const uint4*)(EP + row * 24 + chunk * 8);
      *(uint4*)(H + ((size_t)e * CAP + m0 + wm + row) * DFF + n0 + wn + ni * 16 + chunk * 8) = v;
    }
  }
}

// ---------------- GEMM2: Y[e][slot] = H[e][slot] @ w2[e] + b2[e] -> bf16 (round-4, 113 us) ----
__global__ __launch_bounds__(256) void k_gemm2(
    const unsigned short* __restrict__ H, const unsigned short* __restrict__ w2t,
    const float* __restrict__ b2, unsigned short* __restrict__ Y) {
  __shared__ __align__(16) unsigned short smem[16384];  // 32 KB: 2 bufs x (A 4096 + B 4096)
  int tid = threadIdx.x;
  int lane = tid & 63, wv = tid >> 6;
  int bid = blockIdx.x;
  int e = bid & 7;         // expert pinned to one XCD; its 64 blocks all co-resident there
  int r = bid >> 3;
  int n0 = (r & 7) * 128;
  int m0 = (r >> 3) * 128;

  const unsigned short* gA[2];
  const unsigned short* gB[2];
  int wb[2];
#pragma unroll
  for (int s = 0; s < 2; ++s) {
    int i = s * 256 + tid;
    int row = i >> 2;
    int q = (i & 3) ^ ((i >> 3) & 3);  // pre-swizzled source chunk = c ^ ((row>>1)&3)
    gA[s] = H + ((size_t)e * CAP + m0 + row) * DFF + q * 8;
    gB[s] = w2t + ((size_t)e * DMODEL + n0 + row) * DFF + q * 8;
    wb[s] = (s * 256 + wv * 64) * 8;
  }

  f32x4 zero = {0.f, 0.f, 0.f, 0.f};
  f32x4 acc[4][4];
#pragma unroll
  for (int mi = 0; mi < 4; ++mi)
#pragma unroll
    for (int ni = 0; ni < 4; ++ni) acc[mi][ni] = zero;

  int wm = (wv >> 1) * 64, wn = (wv & 1) * 64;
  int fr = lane & 15, quad = lane >> 4;
  int cs = (quad ^ ((fr >> 1) & 3)) * 8;  // conflict-free slot within 64B row
  int aoff = (wm + fr) * 32 + cs;
  int boff = (wn + fr) * 32 + cs;

#pragma unroll
  for (int s = 0; s < 2; ++s) {   // prologue: stage slice 0 into buf0
    load_lds16(gA[s], smem + wb[s]);
    load_lds16(gB[s], smem + 4096 + wb[s]);
  }
  int buf = 0;
  for (int k0 = 32; k0 <= DFF; k0 += 32) {
    __syncthreads();  // drains vmcnt(0): previous stage complete; guards buffer reuse
    int nbuf = buf ^ 8192;
    if (k0 < DFF) {
#pragma unroll
      for (int s = 0; s < 2; ++s) {
        load_lds16(gA[s] + k0, smem + nbuf + wb[s]);
        load_lds16(gB[s] + k0, smem + nbuf + 4096 + wb[s]);
      }
    }
    const unsigned short* Ab = smem + buf;
    const unsigned short* Bb = Ab + 4096;
    bf16x8 av[4], bv[4];
#pragma unroll
    for (int mi = 0; mi < 4; ++mi) av[mi] = *(const bf16x8*)(Ab + aoff + mi * 512);
#pragma unroll
    for (int ni = 0; ni < 4; ++ni) bv[ni] = *(const bf16x8*)(Bb + boff + ni * 512);
#pragma unroll
    for (int mi = 0; mi < 4; ++mi)
#pragma unroll
      for (int ni = 0; ni < 4; ++ni)
        acc[mi][ni] = __builtin_amdgcn_mfma_f32_16x16x32_bf16(bv[ni], av[mi], acc[mi][ni], 0, 0, 0);
    buf = nbuf;
  }
  __syncthreads();

  unsigned short* EP = smem + wv * 1536;
#pragma unroll
  for (int ni = 0; ni < 4; ++ni) {
    float4 b4 = *(const float4*)(b2 + e * DMODEL + n0 + wn + ni * 16 + quad * 4);
#pragma unroll
    for (int mi = 0; mi < 4; ++mi) {
      uint2 p;
      p.x = (unsigned int)f2bf(acc[mi][ni][0] + b4.x) |
            ((unsigned int)f2bf(acc[mi][ni][1] + b4.y) << 16);
      p.y = (unsigned int)f2bf(acc[mi][ni][2] + b4.z) |
            ((unsigned int)f2bf(acc[mi][ni][3] + b4.w) << 16);
      *(uint2*)(EP + (mi * 16 + fr) * 24 + quad * 4) = p;
    }
#pragma unroll
    for (int t = 0; t < 2; ++t) {
      int row = t * 32 + (lane >> 1), chunk = lane & 1;
      uint4 v = *(const uint4*)(EP + row * 24 + chunk * 8);
      *(uint4*)(Y + ((size_t)e * CAP + m0 + wm + row) * DMODEL + n0 + wn + ni * 16 + chunk * 8) = v;
    }
  }
}

// ---------------- combine: out[t] = sum_k gate * Y[slot_k]; also writes zeros + loss ---------
__global__ void k_combine(const unsigned short* __restrict__ Y,
                          const float* __restrict__ egate,
                          const int* __restrict__ tinv,
                          const int* __restrict__ counts,
                          float* __restrict__ out, float* __restrict__ loss_out) {
  int t = blockIdx.x, tid = threadIdx.x;
  int s0 = tinv[2 * t], s1 = tinv[2 * t + 1];
  int d0 = tid * 4;
  float a0 = 0.f, a1 = 0.f, a2 = 0.f, a3 = 0.f;
  if (s0 >= 0) {
    float g = egate[s0];
    uint2 v = *(const uint2*)(Y + (size_t)s0 * DMODEL + d0);
    a0 += g * bfbits2f(v.x & 0xffff); a1 += g * bfbits2f(v.x >> 16);
    a2 += g * bfbits2f(v.y & 0xffff); a3 += g * bfbits2f(v.y >> 16);
  }
  if (s1 >= 0) {
    float g = egate[s1];
    uint2 v = *(const uint2*)(Y + (size_t)s1 * DMODEL + d0);
    a0 += g * bfbits2f(v.x & 0xffff); a1 += g * bfbits2f(v.x >> 16);
    a2 += g * bfbits2f(v.y & 0xffff); a3 += g * bfbits2f(v.y >> 16);
  }
  float4 o = {a0, a1, a2, a3};
  *(float4*)(out + (size_t)t * DMODEL + d0) = o;
  if (t == 0 && tid == 0) {
    float loss = 0.f;
    for (int e = 0; e < NEXP; ++e) {
      float d = (float)counts[e] - 2048.0f;
      loss += d * d;
    }
    loss_out[0] = loss / (8192.0f * 8192.0f);
  }
}

extern "C" void kernel_launch(void* const* d_in, const int* in_sizes, int n_in,
                              void* d_out, int out_size, void* d_ws, size_t ws_size,
                              hipStream_t stream) {
  (void)in_sizes; (void)n_in; (void)out_size;
  const float* x  = (const float*)d_in[0];
  const float* rw = (const float*)d_in[1];
  const float* w1 = (const float*)d_in[2];
  const float* b1 = (const float*)d_in[3];
  const float* w2 = (const float*)d_in[4];
  const float* b2 = (const float*)d_in[5];
  float* out = (float*)d_out;

  char* ws = (char*)d_ws;
  const size_t XB_BYTES = (size_t)T_TOK * DMODEL * 2;          // 16 MiB (xb; Y aliases after gemm1)
  const size_t WT_BYTES = (size_t)NEXP * DFF * DMODEL * 2;     // 64 MiB per weight
  const size_t H_BYTES  = (size_t)NEXP * CAP * DFF * 2;        // 64 MiB
  const size_t SMALL_BYTES = 2 * NEXP * CAP * 4 + 3 * (size_t)T_TOK * 2 * 4 + 64;
  const size_t NEED_FUSED = XB_BYTES + 2 * WT_BYTES + H_BYTES + SMALL_BYTES;  // ~208.3 MiB
  int fused = (ws_size >= NEED_FUSED);

  unsigned short* xb  = (unsigned short*)ws;
  unsigned short* Yb  = xb;                                     // alias: xb dead after gemm1
  unsigned short* w1t = (unsigned short*)(ws + XB_BYTES);
  unsigned short* w2t = fused ? (unsigned short*)(ws + XB_BYTES + WT_BYTES) : w1t;
  char* after_wt = ws + XB_BYTES + (fused ? 2 : 1) * WT_BYTES;
  unsigned short* Hb = (unsigned short*)after_wt;
  char* small = after_wt + H_BYTES;
  int*   etok   = (int*)small;                                  // 32 KB
  float* egate  = (float*)(small + NEXP * CAP * 4);             // 32 KB
  int*   tkidx  = (int*)(small + 2 * NEXP * CAP * 4);           // 64 KB
  float* tkw    = (float*)(small + 2 * NEXP * CAP * 4 + T_TOK * 2 * 4);  // 64 KB
  int*   tinv   = (int*)(small + 2 * NEXP * CAP * 4 + 2 * T_TOK * 2 * 4);// 64 KB
  int*   counts = (int*)(small + 2 * NEXP * CAP * 4 + 3 * T_TOK * 2 * 4);// 32 B

  // fused prep: router + transpose(w1) [+ transpose(w2) if workspace allows]
  int prep_blocks = 2048 + 8192 + (fused ? 8192 : 0);
  k_prep<<<prep_blocks, 256, 0, stream>>>(x, rw, xb, tkidx, tkw, tinv, w1, w1t, w2, w2t);
  k_scan<<<NEXP, 1024, 0, stream>>>(tkidx, tkw, etok, egate, tinv, counts);
  k_gemm1<<<NEXP * 256, 256, 0, stream>>>(xb, w1t, b1, etok, Hb);
  if (!fused) {
    k_transpose_cvt<<<dim3(DMODEL / 64, DFF / 64, NEXP), 256, 0, stream>>>(w2, w2t, DFF, DMODEL);
  }
  k_gemm2<<<NEXP * 64, 256, 0, stream>>>(Hb, w2t, b2, Yb);
  k_combine<<<T_TOK, 256, 0, stream>>>(Yb, egate, tinv, counts, out,
                                       out + (size_t)T_TOK * DMODEL);
}